// Round 7
// baseline (161.578 us; speedup 1.0000x reference)
//
#include <hip/hip_runtime.h>
#include <math.h>

#define F_IN 256
#define F_OUT 64
#define NEG_SLOPE 0.01f
#define CAP 8192          // fixed capacity per coarse bucket (mean 4096, sigma 64)
#define SB 512            // scatter blocks (256 threads each)

typedef unsigned short ushort8_t __attribute__((ext_vector_type(8)));
typedef __bf16 bf16x8 __attribute__((ext_vector_type(8)));
typedef float f32x16 __attribute__((ext_vector_type(16)));

__device__ inline unsigned short f2bf(float f) {   // RNE
    unsigned u = __float_as_uint(f);
    u += 0x7FFF + ((u >> 16) & 1);
    return (unsigned short)(u >> 16);
}
__device__ inline float bf2f(unsigned short u) {
    return __uint_as_float(((unsigned)u) << 16);
}
// fp32 -> bf16 hi + bf16 lo (hi+lo ~ 2^-17 rel accurate)
__device__ inline void splitbf(float x, unsigned short& hi, unsigned short& lo) {
    hi = f2bf(x);
    lo = f2bf(x - bf2f(hi));
}
__device__ inline bf16x8 asbf8(ushort8_t u) {
    union { ushort8_t u; bf16x8 b; } c; c.u = u; return c.b;
}
__device__ inline float redq32(float v) {   // sum over the 32 lanes of a q-half
    v += __shfl_xor(v, 1);  v += __shfl_xor(v, 2);  v += __shfl_xor(v, 4);
    v += __shfl_xor(v, 8);  v += __shfl_xor(v, 16);
    return v;
}

// ---------------------------------------------------------------------------
// K1: prep frags (W1/W2 -> bf16 hi/lo MFMA B-fragments) + cursor zero.
// Tiny (~3us) but gates mlp, so it runs alone; folds the cursor memset
// (block 0) to drop the hipMemsetAsync dispatch.
// 32x32x16 B layout: B[k][n]: n = lane&31, k = (lane>>5)*8 + j.
// w1frag[((gks*2+nt)*64 + lane)*8 + j] covers f = nt*32+(lane&31),
// k = gks*16 + (lane>>5)*8 + j  (gks 0..15). w2frag same with K=64.
// ---------------------------------------------------------------------------
__global__ __launch_bounds__(256)
void prep_kernel(const float* __restrict__ W1, const float* __restrict__ W2,
                 unsigned short* __restrict__ w1fh, unsigned short* __restrict__ w1fl,
                 unsigned short* __restrict__ w2fh, unsigned short* __restrict__ w2fl,
                 int* __restrict__ cursor)
{
    int idx = blockIdx.x * 256 + threadIdx.x;   // 0..16383
    if (blockIdx.x == 0) cursor[threadIdx.x] = 0;
    int jj = idx & 7, l = (idx >> 3) & 63, t = idx >> 9;
    {
        int nt = t & 1, gks = t >> 1;
        int f = nt * 32 + (l & 31);
        int k = gks * 16 + (l >> 5) * 8 + jj;
        unsigned short hi, lo;
        splitbf(W1[f * F_IN + k], hi, lo);
        w1fh[idx] = hi; w1fl[idx] = lo;
    }
    if (idx < 4096) {
        int nt = t & 1, ks = t >> 1;   // t 0..7
        int f = nt * 32 + (l & 31);
        int j = ks * 16 + (l >> 5) * 8 + jj;
        unsigned short hi, lo;
        splitbf(W2[f * F_OUT + j], hi, lo);
        w2fh[idx] = hi; w2fl[idx] = lo;
    }
}

// ---------------------------------------------------------------------------
// K2: mlp UNION scatter, interleaved 1:1 (R13). mlp (node MLP) and scatter
// (edge bucketing) are fully independent -> co-resident blocks overlap the
// MFMA/LDS-heavy mlp with the atomic/streaming scatter: t ~ max, not sum.
// bid<2*MLPB: even = mlp(bid>>1), odd = scatter(bid>>1); tail = scatter.
//
// mlp (R12 structure): per-wave-private LDS staging, barrier-free. Per
// K-half: 16 coalesced float4 loads (2 rows/instr), register hi/lo split,
// ds_write to stride-134 (odd-dw) private buffer, 8 ksteps of ds_read_b128
// + 6 MFMAs. z transpose for GEMM2 aliases the same region. Scores via
// in-register 32-lane xor-tree; hb stored from registers.
//
// scatter: per-block LDS hist of dst>>8, ONE global atomicAdd per
// (block,bucket) reserves a sub-range in the bucket's CAP region, then
// LDS-cursor scatter. LDS arrays alias zbuf (halves never coexist).
// ---------------------------------------------------------------------------
__global__ __launch_bounds__(256, 2)
void mlp_scatter_kernel(const float* __restrict__ x,
                        const unsigned short* __restrict__ w1fh,
                        const unsigned short* __restrict__ w1fl,
                        const unsigned short* __restrict__ w2fh,
                        const unsigned short* __restrict__ w2fl,
                        const float* __restrict__ a,
                        unsigned short* __restrict__ hb,
                        float* __restrict__ sdst,
                        float* __restrict__ ssrc, int N,
                        const int* __restrict__ src, const int* __restrict__ dst,
                        int* __restrict__ cursor, int* __restrict__ edata,
                        int E, int chunk, int MLPB)
{
    // per-wave region: 8576 ushorts (17152B). x-stage: xh[32][134] at +0,
    // xl[32][134] at +4288. GEMM2 z: zh[32][66] at +0, zl at +2112 (alias,
    // wave-sequential -> safe). Scatter aliases the same buffer.
    __shared__ __align__(16) unsigned short zbuf[4 * 8576];

    const int tid = threadIdx.x;
    const int lane = tid & 63;
    const int bid = blockIdx.x;

    int mbid, sbid;
    if (bid < 2 * MLPB) {
        mbid = ((bid & 1) == 0) ? (bid >> 1) : -1;
        sbid = ((bid & 1) == 1) ? (bid >> 1) : -1;
    } else {
        mbid = -1;
        sbid = bid - MLPB;
    }

    if (mbid >= 0) {   // ---- mlp half ----
        const int wid = __builtin_amdgcn_readfirstlane(tid >> 6);
        const int ml = lane & 31;          // node index within wave tile
        const int q = lane >> 5;           // K-octet selector
        const int hl = lane >> 5;          // row parity for staging loads
        const int cl = lane & 31;          // col group for staging loads
        const int node0w = mbid * 128 + wid * 32;

        unsigned short* xh = zbuf + wid * 8576;
        unsigned short* xl = xh + 4288;
        unsigned short* zh = xh;           // aliases (sequential use)
        unsigned short* zl = xh + 2112;

        f32x16 acc0, acc1;
#pragma unroll
        for (int i = 0; i < 16; i++) { acc0[i] = 0.f; acc1[i] = 0.f; }

        // ---- GEMM1: z = relu(x @ W1^T), K=256 as 2 halves x 8 ksteps ----
#pragma unroll
        for (int half = 0; half < 2; half++) {
            float4 v[16];
#pragma unroll
            for (int i = 0; i < 16; i++) {
                int r = 2 * i + hl;
                int rr = min(node0w + r, N - 1);
                v[i] = *(const float4*)(x + (size_t)rr * F_IN + half * 128 + cl * 4);
            }
#pragma unroll
            for (int i = 0; i < 16; i++) {
                int r = 2 * i + hl;
                ushort4 h4, l4;
                unsigned short th, tl;
                splitbf(v[i].x, th, tl); h4.x = th; l4.x = tl;
                splitbf(v[i].y, th, tl); h4.y = th; l4.y = tl;
                splitbf(v[i].z, th, tl); h4.z = th; l4.z = tl;
                splitbf(v[i].w, th, tl); h4.w = th; l4.w = tl;
                *(ushort4*)(xh + r * 134 + cl * 4) = h4;
                *(ushort4*)(xl + r * 134 + cl * 4) = l4;
            }
#pragma unroll
            for (int ks = 0; ks < 8; ks++) {
                int gks = half * 8 + ks;
                bf16x8 ah = asbf8(*(const ushort8_t*)(xh + ml * 134 + ks * 16 + q * 8));
                bf16x8 al = asbf8(*(const ushort8_t*)(xl + ml * 134 + ks * 16 + q * 8));
                bf16x8 bh0 = asbf8(*(const ushort8_t*)(w1fh + ((gks * 2 + 0) * 64 + lane) * 8));
                bf16x8 bl0 = asbf8(*(const ushort8_t*)(w1fl + ((gks * 2 + 0) * 64 + lane) * 8));
                bf16x8 bh1 = asbf8(*(const ushort8_t*)(w1fh + ((gks * 2 + 1) * 64 + lane) * 8));
                bf16x8 bl1 = asbf8(*(const ushort8_t*)(w1fl + ((gks * 2 + 1) * 64 + lane) * 8));
                acc0 = __builtin_amdgcn_mfma_f32_32x32x16_bf16(ah, bh0, acc0, 0, 0, 0);
                acc0 = __builtin_amdgcn_mfma_f32_32x32x16_bf16(ah, bl0, acc0, 0, 0, 0);
                acc0 = __builtin_amdgcn_mfma_f32_32x32x16_bf16(al, bh0, acc0, 0, 0, 0);
                acc1 = __builtin_amdgcn_mfma_f32_32x32x16_bf16(ah, bh1, acc1, 0, 0, 0);
                acc1 = __builtin_amdgcn_mfma_f32_32x32x16_bf16(ah, bl1, acc1, 0, 0, 0);
                acc1 = __builtin_amdgcn_mfma_f32_32x32x16_bf16(al, bh1, acc1, 0, 0, 0);
            }
        }

        // ---- z -> per-wave LDS (hi/lo), C layout: col(feat)=lane&31,
        // row(node) = (reg&3)+8*(reg>>2)+4*q ----
#pragma unroll
        for (int reg = 0; reg < 16; reg++) {
            int nd = (reg & 3) + 8 * (reg >> 2) + 4 * q;
            float z0 = fmaxf(acc0[reg], 0.f);
            float z1 = fmaxf(acc1[reg], 0.f);
            unsigned short h_, l_;
            splitbf(z0, h_, l_);
            zh[nd * 66 + ml] = h_; zl[nd * 66 + ml] = l_;
            splitbf(z1, h_, l_);
            zh[nd * 66 + 32 + ml] = h_; zl[nd * 66 + 32 + ml] = l_;
        }
        // wave-private region: lgkmcnt orders the dependent ds_read.

        // ---- GEMM2: h = relu(z @ W2^T), K=64 as 4 MFMA k-steps ----
        f32x16 hacc0, hacc1;
#pragma unroll
        for (int i = 0; i < 16; i++) { hacc0[i] = 0.f; hacc1[i] = 0.f; }
#pragma unroll
        for (int ks = 0; ks < 4; ks++) {
            bf16x8 wh0 = asbf8(*(const ushort8_t*)(w2fh + ((ks * 2 + 0) * 64 + lane) * 8));
            bf16x8 wl0 = asbf8(*(const ushort8_t*)(w2fl + ((ks * 2 + 0) * 64 + lane) * 8));
            bf16x8 wh1 = asbf8(*(const ushort8_t*)(w2fh + ((ks * 2 + 1) * 64 + lane) * 8));
            bf16x8 wl1 = asbf8(*(const ushort8_t*)(w2fl + ((ks * 2 + 1) * 64 + lane) * 8));
            bf16x8 ah = asbf8(*(const ushort8_t*)(zh + ml * 66 + ks * 16 + q * 8));
            bf16x8 al = asbf8(*(const ushort8_t*)(zl + ml * 66 + ks * 16 + q * 8));
            hacc0 = __builtin_amdgcn_mfma_f32_32x32x16_bf16(ah, wh0, hacc0, 0, 0, 0);
            hacc0 = __builtin_amdgcn_mfma_f32_32x32x16_bf16(ah, wl0, hacc0, 0, 0, 0);
            hacc0 = __builtin_amdgcn_mfma_f32_32x32x16_bf16(al, wh0, hacc0, 0, 0, 0);
            hacc1 = __builtin_amdgcn_mfma_f32_32x32x16_bf16(ah, wh1, hacc1, 0, 0, 0);
            hacc1 = __builtin_amdgcn_mfma_f32_32x32x16_bf16(ah, wl1, hacc1, 0, 0, 0);
            hacc1 = __builtin_amdgcn_mfma_f32_32x32x16_bf16(al, wh1, hacc1, 0, 0, 0);
        }

        // ---- epilogue: scores via in-register xor-tree, hb from regs ----
        const float aD0 = a[ml],            aD1 = a[32 + ml];
        const float aS0 = a[F_OUT + ml],    aS1 = a[F_OUT + 32 + ml];

        float sdv = 0.f, ssv = 0.f;
#pragma unroll
        for (int reg = 0; reg < 16; reg++) {
            int nd = (reg & 3) + 8 * (reg >> 2) + 4 * q;
            float h0 = fmaxf(hacc0[reg], 0.f);
            float h1 = fmaxf(hacc1[reg], 0.f);
            float td = redq32(h0 * aD0 + h1 * aD1);
            float ts = redq32(h0 * aS0 + h1 * aS1);
            if (ml == nd) { sdv = td; ssv = ts; }
            int gn = node0w + nd;
            if (gn < N) {
                hb[(size_t)gn * F_OUT + ml]      = f2bf(h0);
                hb[(size_t)gn * F_OUT + 32 + ml] = f2bf(h1);
            }
        }
        {
            int gn = node0w + ml;
            if ((((ml >> 2) & 1) == q) && gn < N) {
                sdst[gn] = sdv;
                ssrc[gn] = ssv;
            }
        }
        return;
    }

    // ---- scatter half (256 threads) ----
    int* lh = (int*)zbuf;
    int* lbase = lh + 256;
    int* lcur = lh + 512;
    lh[tid] = 0;
    __syncthreads();
    const int beg = sbid * chunk;
    const int end = min(E, beg + chunk);
    for (int i = beg + tid; i < end; i += 256)
        atomicAdd(&lh[((unsigned)dst[i]) >> 8], 1);
    __syncthreads();
    {
        int c = lh[tid];
        lbase[tid] = c ? atomicAdd(&cursor[tid], c) : 0;
        lcur[tid] = 0;
    }
    __syncthreads();
    for (int i = beg + tid; i < end; i += 256) {
        int d = dst[i];
        int s = src[i];
        int b = ((unsigned)d) >> 8;
        int rk = atomicAdd(&lcur[b], 1);
        edata[b * CAP + lbase[b] + rk] = ((d & 0xFF) << 16) | s;
    }
}

// ---------------------------------------------------------------------------
// K3: sort+aggregate fused per bucket (R13). Block cb counting-sorts its
// bucket INTO LDS (src < 65536 fits ushort; CAP*2B = 16KB) and immediately
// aggregates its 256 dst nodes. Deletes the ssorted/cnt/offs global
// round-trips, one dispatch, and one launch gap.
// Aggregate structure = R10: 16-lane node groups, ushort4 row gathers.
// 1024 threads = 64 groups x 4 sequential nodes.
// ---------------------------------------------------------------------------
__global__ __launch_bounds__(1024)
void sortagg_kernel(const int* __restrict__ cursor,
                    const int* __restrict__ edata,
                    const unsigned short* __restrict__ hb,
                    const float* __restrict__ sdst,
                    const float* __restrict__ ssrc,
                    float* __restrict__ out, int N)
{
    __shared__ int hist[256];
    __shared__ int excl[256];
    __shared__ int start_s[256];
    __shared__ unsigned short ssl[CAP];
    __shared__ float2 ws_sh[16][64];

    const int tid = threadIdx.x;
    const int lane = tid & 63;
    const int wid = tid >> 6;
    const int cb = blockIdx.x;
    const int base = cb * CAP;
    const int ecnt = cursor[cb];

    if (tid < 256) hist[tid] = 0;
    __syncthreads();
    for (int i = tid; i < ecnt; i += 1024)
        atomicAdd(&hist[((unsigned)edata[base + i]) >> 16], 1);
    __syncthreads();

    if (tid < 64) {
        int v0 = hist[lane * 4], v1 = hist[lane * 4 + 1];
        int v2 = hist[lane * 4 + 2], v3 = hist[lane * 4 + 3];
        int ts = v0 + v1 + v2 + v3;
        int s = ts;
#pragma unroll
        for (int d = 1; d < 64; d <<= 1) {
            int t = __shfl_up(s, d);
            if (lane >= d) s += t;
        }
        int e = s - ts;
        excl[lane * 4] = e;
        excl[lane * 4 + 1] = e + v0;
        excl[lane * 4 + 2] = e + v0 + v1;
        excl[lane * 4 + 3] = e + v0 + v1 + v2;
    }
    __syncthreads();
    if (tid < 256) start_s[tid] = excl[tid];
    __syncthreads();

    for (int i = tid; i < ecnt; i += 1024) {
        int pack = edata[base + i];
        int low = ((unsigned)pack) >> 16;
        int rk = atomicAdd(&excl[low], 1);
        ssl[rk] = (unsigned short)(pack & 0xFFFF);
    }
    __syncthreads();

    // ---- aggregate 256 dst nodes: 64 groups x 4 reps ----
    const int g = lane >> 4;          // group within wave (0..3)
    const int li = lane & 15;         // lane within group
    const int grp = wid * 4 + g;      // 0..63

    for (int rep = 0; rep < 4; rep++) {
        const int local = rep * 64 + grp;
        const int d = cb * 256 + local;
        const bool vd = d < N;
        const int off = vd ? start_s[local] : 0;
        const int deg = vd ? hist[local] : 0;
        const float sdd = vd ? sdst[d] : 0.f;

        float M = -INFINITY, S = 0.f;
        float c0 = 0.f, c1 = 0.f, c2 = 0.f, c3 = 0.f;

        for (int ch = 0; ch < deg; ch += 16) {
            int ce = min(16, deg - ch);
            float score = -INFINITY;
            int s = 0;
            if (li < ce) {
                s = ssl[off + ch + li];
                float sc = sdd + ssrc[s];
                score = sc > 0.f ? sc : NEG_SLOPE * sc;
            }
            float mc = score;
            mc = fmaxf(mc, __shfl_xor(mc, 1));
            mc = fmaxf(mc, __shfl_xor(mc, 2));
            mc = fmaxf(mc, __shfl_xor(mc, 4));
            mc = fmaxf(mc, __shfl_xor(mc, 8));
            float newM = fmaxf(M, mc);
            float scale = __expf(M - newM);
            float w = (li < ce) ? __expf(score - newM) : 0.f;
            ws_sh[wid][lane] = make_float2(w, __int_as_float(s));
            float csum = w;
            csum += __shfl_xor(csum, 1);
            csum += __shfl_xor(csum, 2);
            csum += __shfl_xor(csum, 4);
            csum += __shfl_xor(csum, 8);
            S = S * scale + csum;
            __builtin_amdgcn_wave_barrier();

            float t0 = 0.f, t1 = 0.f, t2 = 0.f, t3 = 0.f;
#pragma unroll
            for (int e = 0; e < 16; e++) {
                float2 tw = ws_sh[wid][g * 16 + e];
                int se = __float_as_int(tw.y);
                ushort4 r = *(const ushort4*)(hb + (((size_t)(unsigned)se) << 6) + li * 4);
                t0 = fmaf(tw.x, bf2f(r.x), t0);
                t1 = fmaf(tw.x, bf2f(r.y), t1);
                t2 = fmaf(tw.x, bf2f(r.z), t2);
                t3 = fmaf(tw.x, bf2f(r.w), t3);
            }
            c0 = c0 * scale + t0;
            c1 = c1 * scale + t1;
            c2 = c2 * scale + t2;
            c3 = c3 * scale + t3;
            __builtin_amdgcn_wave_barrier();
            M = newM;
        }

        if (vd) {
            ushort4 hr = *(const ushort4*)(hb + (((size_t)(unsigned)d) << 6) + li * 4);
            float inv = (S > 0.f) ? 1.f / S : 0.f;
            float r0 = bf2f(hr.x) - c0 * inv;
            float r1 = bf2f(hr.y) - c1 * inv;
            float r2 = bf2f(hr.z) - c2 * inv;
            float r3 = bf2f(hr.w) - c3 * inv;
            float4 o;
            o.x = r0 > 0.f ? r0 : 0.f;
            o.y = r1 > 0.f ? r1 : 0.f;
            o.z = r2 > 0.f ? r2 : 0.f;
            o.w = r3 > 0.f ? r3 : 0.f;
            *(float4*)(out + (size_t)d * F_OUT + li * 4) = o;
        }
    }
}

// ---------------------------------------------------------------------------
extern "C" void kernel_launch(void* const* d_in, const int* in_sizes, int n_in,
                              void* d_out, int out_size, void* d_ws,
                              size_t ws_size, hipStream_t stream)
{
    const float* x  = (const float*)d_in[0];
    const float* W1 = (const float*)d_in[1];
    const float* W2 = (const float*)d_in[2];
    const float* a  = (const float*)d_in[3];
    const int* src  = (const int*)d_in[4];
    const int* dst  = (const int*)d_in[5];
    const int N = in_sizes[0] / F_IN;   // 50000
    const int E = in_sizes[4];          // 800000

    float* ws = (float*)d_ws;
    float* sdst = ws;                                   // N
    float* ssrc = sdst + N;                             // N
    unsigned short* w1fh = (unsigned short*)(ssrc + N); // 16384 us
    unsigned short* w1fl = w1fh + 16384;                // 16384 us
    unsigned short* w2fh = w1fl + 16384;                // 4096 us
    unsigned short* w2fl = w2fh + 4096;                 // 4096 us
    unsigned short* hb = w2fl + 4096;                   // N*64 us
    int* cursor = (int*)(hb + (size_t)N * F_OUT);       // 256
    int* edata  = cursor + 256;                         // 196*CAP

    const int nbc = (N + 255) >> 8;                     // 196
    const int MLPB = (N + 127) >> 7;                    // 391
    const int chunk = (E + SB - 1) / SB;                // 1563

    prep_kernel<<<64, 256, 0, stream>>>(W1, W2, w1fh, w1fl, w2fh, w2fl, cursor);
    mlp_scatter_kernel<<<MLPB + SB, 256, 0, stream>>>(x, w1fh, w1fl, w2fh, w2fl, a,
                                                      hb, sdst, ssrc, N,
                                                      src, dst, cursor, edata,
                                                      E, chunk, MLPB);
    sortagg_kernel<<<nbc, 1024, 0, stream>>>(cursor, edata, hb, sdst, ssrc,
                                             (float*)d_out, N);
}

// Round 8
// 147.866 us; speedup vs baseline: 1.0927x; 1.0927x over previous
//
#include <hip/hip_runtime.h>
#include <math.h>

#define F_IN 256
#define F_OUT 64
#define NEG_SLOPE 0.01f
#define CAP 8192          // fixed capacity per coarse bucket (mean 4096, sigma 64)
#define SB 64             // scatter blocks (256 threads each) appended to mlp grid

typedef unsigned short ushort8_t __attribute__((ext_vector_type(8)));
typedef __bf16 bf16x8 __attribute__((ext_vector_type(8)));
typedef float f32x16 __attribute__((ext_vector_type(16)));

__device__ inline unsigned short f2bf(float f) {   // RNE
    unsigned u = __float_as_uint(f);
    u += 0x7FFF + ((u >> 16) & 1);
    return (unsigned short)(u >> 16);
}
__device__ inline float bf2f(unsigned short u) {
    return __uint_as_float(((unsigned)u) << 16);
}
// fp32 -> bf16 hi + bf16 lo (hi+lo ~ 2^-17 rel accurate)
__device__ inline void splitbf(float x, unsigned short& hi, unsigned short& lo) {
    hi = f2bf(x);
    lo = f2bf(x - bf2f(hi));
}
__device__ inline bf16x8 asbf8(ushort8_t u) {
    union { ushort8_t u; bf16x8 b; } c; c.u = u; return c.b;
}
__device__ inline float redq32(float v) {   // sum over the 32 lanes of a q-half
    v += __shfl_xor(v, 1);  v += __shfl_xor(v, 2);  v += __shfl_xor(v, 4);
    v += __shfl_xor(v, 8);  v += __shfl_xor(v, 16);
    return v;
}

// ---------------------------------------------------------------------------
// K1: prep frags (W1/W2 -> bf16 hi/lo MFMA B-fragments) + cursor zero.
// 32x32x16 B layout: B[k][n]: n = lane&31, k = (lane>>5)*8 + j.
// w1frag[((gks*2+nt)*64 + lane)*8 + j] covers f = nt*32+(lane&31),
// k = gks*16 + (lane>>5)*8 + j  (gks 0..15). w2frag same with K=64.
// ---------------------------------------------------------------------------
__global__ __launch_bounds__(256)
void prep_kernel(const float* __restrict__ W1, const float* __restrict__ W2,
                 unsigned short* __restrict__ w1fh, unsigned short* __restrict__ w1fl,
                 unsigned short* __restrict__ w2fh, unsigned short* __restrict__ w2fl,
                 int* __restrict__ cursor)
{
    int idx = blockIdx.x * 256 + threadIdx.x;   // 0..16383
    if (blockIdx.x == 0) cursor[threadIdx.x] = 0;
    int jj = idx & 7, l = (idx >> 3) & 63, t = idx >> 9;
    {
        int nt = t & 1, gks = t >> 1;
        int f = nt * 32 + (l & 31);
        int k = gks * 16 + (l >> 5) * 8 + jj;
        unsigned short hi, lo;
        splitbf(W1[f * F_IN + k], hi, lo);
        w1fh[idx] = hi; w1fl[idx] = lo;
    }
    if (idx < 4096) {
        int nt = t & 1, ks = t >> 1;   // t 0..7
        int f = nt * 32 + (l & 31);
        int j = ks * 16 + (l >> 5) * 8 + jj;
        unsigned short hi, lo;
        splitbf(W2[f * F_OUT + j], hi, lo);
        w2fh[idx] = hi; w2fl[idx] = lo;
    }
}

// ---------------------------------------------------------------------------
// K2: mlp (blocks 0..MLPB-1) + scatter (ONLY SB=64 appended blocks).
// R7 lesson: 1:1 interleave made 50% of resident blocks scatter blocks each
// holding the kernel's full 68.6KB LDS for 3KB of work -> occupancy 10.6%.
// With 64 scatter blocks the LDS waste is ~14% of blocks and scatter's
// ~10us hides under mlp. No data coupling between the halves.
//
// mlp (R12/R6 structure, verified <=41us): per-wave-private LDS staging,
// barrier-free. Per K-half: 16 coalesced float4 loads (2 rows/instr, 512B
// contiguous per row-half), register hi/lo split, ds_write to stride-134
// (odd-dw) private buffer, 8 ksteps of ds_read_b128 + 6 MFMAs. z transpose
// for GEMM2 aliases the same region (wave-sequential). Scores via
// in-register 32-lane xor-tree; hb stored from registers.
//
// scatter: per-block LDS hist of dst>>8, ONE global atomicAdd per
// (block,bucket) reserves a sub-range in the bucket's CAP region, then
// LDS-cursor scatter (chunk = E/64 = 12500 edges/block).
// ---------------------------------------------------------------------------
__global__ __launch_bounds__(256, 2)
void mlp_scatter_kernel(const float* __restrict__ x,
                        const unsigned short* __restrict__ w1fh,
                        const unsigned short* __restrict__ w1fl,
                        const unsigned short* __restrict__ w2fh,
                        const unsigned short* __restrict__ w2fl,
                        const float* __restrict__ a,
                        unsigned short* __restrict__ hb,
                        float* __restrict__ sdst,
                        float* __restrict__ ssrc, int N,
                        const int* __restrict__ src, const int* __restrict__ dst,
                        int* __restrict__ cursor, int* __restrict__ edata,
                        int E, int chunk, int MLPB)
{
    // per-wave region: 8576 ushorts (17152B). x-stage: xh[32][134] at +0,
    // xl[32][134] at +4288. GEMM2 z: zh[32][66] at +0, zl at +2112 (alias,
    // wave-sequential -> safe). Scatter blocks alias as int arrays.
    __shared__ __align__(16) unsigned short zbuf[4 * 8576];

    const int tid = threadIdx.x;
    const int lane = tid & 63;
    const int bid = blockIdx.x;

    if (bid < MLPB) {   // ---- mlp half ----
        const int wid = __builtin_amdgcn_readfirstlane(tid >> 6);
        const int ml = lane & 31;          // node index within wave tile
        const int q = lane >> 5;           // K-octet selector
        const int hl = lane >> 5;          // row parity for staging loads
        const int cl = lane & 31;          // col group for staging loads
        const int node0w = bid * 128 + wid * 32;

        unsigned short* xh = zbuf + wid * 8576;
        unsigned short* xl = xh + 4288;
        unsigned short* zh = xh;           // aliases (sequential use)
        unsigned short* zl = xh + 2112;

        f32x16 acc0, acc1;
#pragma unroll
        for (int i = 0; i < 16; i++) { acc0[i] = 0.f; acc1[i] = 0.f; }

        // ---- GEMM1: z = relu(x @ W1^T), K=256 as 2 halves x 8 ksteps ----
#pragma unroll
        for (int half = 0; half < 2; half++) {
            float4 v[16];
#pragma unroll
            for (int i = 0; i < 16; i++) {
                int r = 2 * i + hl;
                int rr = min(node0w + r, N - 1);
                v[i] = *(const float4*)(x + (size_t)rr * F_IN + half * 128 + cl * 4);
            }
#pragma unroll
            for (int i = 0; i < 16; i++) {
                int r = 2 * i + hl;
                ushort4 h4, l4;
                unsigned short th, tl;
                splitbf(v[i].x, th, tl); h4.x = th; l4.x = tl;
                splitbf(v[i].y, th, tl); h4.y = th; l4.y = tl;
                splitbf(v[i].z, th, tl); h4.z = th; l4.z = tl;
                splitbf(v[i].w, th, tl); h4.w = th; l4.w = tl;
                *(ushort4*)(xh + r * 134 + cl * 4) = h4;
                *(ushort4*)(xl + r * 134 + cl * 4) = l4;
            }
#pragma unroll
            for (int ks = 0; ks < 8; ks++) {
                int gks = half * 8 + ks;
                bf16x8 ah = asbf8(*(const ushort8_t*)(xh + ml * 134 + ks * 16 + q * 8));
                bf16x8 al = asbf8(*(const ushort8_t*)(xl + ml * 134 + ks * 16 + q * 8));
                bf16x8 bh0 = asbf8(*(const ushort8_t*)(w1fh + ((gks * 2 + 0) * 64 + lane) * 8));
                bf16x8 bl0 = asbf8(*(const ushort8_t*)(w1fl + ((gks * 2 + 0) * 64 + lane) * 8));
                bf16x8 bh1 = asbf8(*(const ushort8_t*)(w1fh + ((gks * 2 + 1) * 64 + lane) * 8));
                bf16x8 bl1 = asbf8(*(const ushort8_t*)(w1fl + ((gks * 2 + 1) * 64 + lane) * 8));
                acc0 = __builtin_amdgcn_mfma_f32_32x32x16_bf16(ah, bh0, acc0, 0, 0, 0);
                acc0 = __builtin_amdgcn_mfma_f32_32x32x16_bf16(ah, bl0, acc0, 0, 0, 0);
                acc0 = __builtin_amdgcn_mfma_f32_32x32x16_bf16(al, bh0, acc0, 0, 0, 0);
                acc1 = __builtin_amdgcn_mfma_f32_32x32x16_bf16(ah, bh1, acc1, 0, 0, 0);
                acc1 = __builtin_amdgcn_mfma_f32_32x32x16_bf16(ah, bl1, acc1, 0, 0, 0);
                acc1 = __builtin_amdgcn_mfma_f32_32x32x16_bf16(al, bh1, acc1, 0, 0, 0);
            }
        }

        // ---- z -> per-wave LDS (hi/lo), C layout: col(feat)=lane&31,
        // row(node) = (reg&3)+8*(reg>>2)+4*q ----
#pragma unroll
        for (int reg = 0; reg < 16; reg++) {
            int nd = (reg & 3) + 8 * (reg >> 2) + 4 * q;
            float z0 = fmaxf(acc0[reg], 0.f);
            float z1 = fmaxf(acc1[reg], 0.f);
            unsigned short h_, l_;
            splitbf(z0, h_, l_);
            zh[nd * 66 + ml] = h_; zl[nd * 66 + ml] = l_;
            splitbf(z1, h_, l_);
            zh[nd * 66 + 32 + ml] = h_; zl[nd * 66 + 32 + ml] = l_;
        }
        // wave-private region: lgkmcnt orders the dependent ds_read.

        // ---- GEMM2: h = relu(z @ W2^T), K=64 as 4 MFMA k-steps ----
        f32x16 hacc0, hacc1;
#pragma unroll
        for (int i = 0; i < 16; i++) { hacc0[i] = 0.f; hacc1[i] = 0.f; }
#pragma unroll
        for (int ks = 0; ks < 4; ks++) {
            bf16x8 wh0 = asbf8(*(const ushort8_t*)(w2fh + ((ks * 2 + 0) * 64 + lane) * 8));
            bf16x8 wl0 = asbf8(*(const ushort8_t*)(w2fl + ((ks * 2 + 0) * 64 + lane) * 8));
            bf16x8 wh1 = asbf8(*(const ushort8_t*)(w2fh + ((ks * 2 + 1) * 64 + lane) * 8));
            bf16x8 wl1 = asbf8(*(const ushort8_t*)(w2fl + ((ks * 2 + 1) * 64 + lane) * 8));
            bf16x8 ah = asbf8(*(const ushort8_t*)(zh + ml * 66 + ks * 16 + q * 8));
            bf16x8 al = asbf8(*(const ushort8_t*)(zl + ml * 66 + ks * 16 + q * 8));
            hacc0 = __builtin_amdgcn_mfma_f32_32x32x16_bf16(ah, wh0, hacc0, 0, 0, 0);
            hacc0 = __builtin_amdgcn_mfma_f32_32x32x16_bf16(ah, wl0, hacc0, 0, 0, 0);
            hacc0 = __builtin_amdgcn_mfma_f32_32x32x16_bf16(al, wh0, hacc0, 0, 0, 0);
            hacc1 = __builtin_amdgcn_mfma_f32_32x32x16_bf16(ah, wh1, hacc1, 0, 0, 0);
            hacc1 = __builtin_amdgcn_mfma_f32_32x32x16_bf16(ah, wl1, hacc1, 0, 0, 0);
            hacc1 = __builtin_amdgcn_mfma_f32_32x32x16_bf16(al, wh1, hacc1, 0, 0, 0);
        }

        // ---- epilogue: scores via in-register xor-tree, hb from regs ----
        const float aD0 = a[ml],            aD1 = a[32 + ml];
        const float aS0 = a[F_OUT + ml],    aS1 = a[F_OUT + 32 + ml];

        float sdv = 0.f, ssv = 0.f;
#pragma unroll
        for (int reg = 0; reg < 16; reg++) {
            int nd = (reg & 3) + 8 * (reg >> 2) + 4 * q;
            float h0 = fmaxf(hacc0[reg], 0.f);
            float h1 = fmaxf(hacc1[reg], 0.f);
            float td = redq32(h0 * aD0 + h1 * aD1);
            float ts = redq32(h0 * aS0 + h1 * aS1);
            if (ml == nd) { sdv = td; ssv = ts; }
            int gn = node0w + nd;
            if (gn < N) {
                hb[(size_t)gn * F_OUT + ml]      = f2bf(h0);
                hb[(size_t)gn * F_OUT + 32 + ml] = f2bf(h1);
            }
        }
        {
            int gn = node0w + ml;
            if ((((ml >> 2) & 1) == q) && gn < N) {
                sdst[gn] = sdv;
                ssrc[gn] = ssv;
            }
        }
        return;
    }

    // ---- scatter half (SB blocks, 256 threads) ----
    const int sbid = bid - MLPB;
    int* lh = (int*)zbuf;
    int* lbase = lh + 256;
    int* lcur = lh + 512;
    lh[tid] = 0;
    __syncthreads();
    const int beg = sbid * chunk;
    const int end = min(E, beg + chunk);
    for (int i = beg + tid; i < end; i += 256)
        atomicAdd(&lh[((unsigned)dst[i]) >> 8], 1);
    __syncthreads();
    {
        int c = lh[tid];
        lbase[tid] = c ? atomicAdd(&cursor[tid], c) : 0;
        lcur[tid] = 0;
    }
    __syncthreads();
    for (int i = beg + tid; i < end; i += 256) {
        int d = dst[i];
        int s = src[i];
        int b = ((unsigned)d) >> 8;
        int rk = atomicAdd(&lcur[b], 1);
        edata[b * CAP + lbase[b] + rk] = ((d & 0xFF) << 16) | s;
    }
}

// ---------------------------------------------------------------------------
// K3: sort+aggregate fused per bucket (R7-verified). Block cb counting-sorts
// its bucket INTO LDS (src < 65536 fits ushort; CAP*2B = 16KB) and
// immediately aggregates its 256 dst nodes. No ssorted/cnt/offs globals.
// Aggregate structure = R10: 16-lane node groups, ushort4 row gathers.
// 1024 threads = 64 groups x 4 sequential nodes.
// ---------------------------------------------------------------------------
__global__ __launch_bounds__(1024)
void sortagg_kernel(const int* __restrict__ cursor,
                    const int* __restrict__ edata,
                    const unsigned short* __restrict__ hb,
                    const float* __restrict__ sdst,
                    const float* __restrict__ ssrc,
                    float* __restrict__ out, int N)
{
    __shared__ int hist[256];
    __shared__ int excl[256];
    __shared__ int start_s[256];
    __shared__ unsigned short ssl[CAP];
    __shared__ float2 ws_sh[16][64];

    const int tid = threadIdx.x;
    const int lane = tid & 63;
    const int wid = tid >> 6;
    const int cb = blockIdx.x;
    const int base = cb * CAP;
    const int ecnt = cursor[cb];

    if (tid < 256) hist[tid] = 0;
    __syncthreads();
    for (int i = tid; i < ecnt; i += 1024)
        atomicAdd(&hist[((unsigned)edata[base + i]) >> 16], 1);
    __syncthreads();

    if (tid < 64) {
        int v0 = hist[lane * 4], v1 = hist[lane * 4 + 1];
        int v2 = hist[lane * 4 + 2], v3 = hist[lane * 4 + 3];
        int ts = v0 + v1 + v2 + v3;
        int s = ts;
#pragma unroll
        for (int d = 1; d < 64; d <<= 1) {
            int t = __shfl_up(s, d);
            if (lane >= d) s += t;
        }
        int e = s - ts;
        excl[lane * 4] = e;
        excl[lane * 4 + 1] = e + v0;
        excl[lane * 4 + 2] = e + v0 + v1;
        excl[lane * 4 + 3] = e + v0 + v1 + v2;
    }
    __syncthreads();
    if (tid < 256) start_s[tid] = excl[tid];
    __syncthreads();

    for (int i = tid; i < ecnt; i += 1024) {
        int pack = edata[base + i];
        int low = ((unsigned)pack) >> 16;
        int rk = atomicAdd(&excl[low], 1);
        ssl[rk] = (unsigned short)(pack & 0xFFFF);
    }
    __syncthreads();

    // ---- aggregate 256 dst nodes: 64 groups x 4 reps ----
    const int g = lane >> 4;          // group within wave (0..3)
    const int li = lane & 15;         // lane within group
    const int grp = wid * 4 + g;      // 0..63

    for (int rep = 0; rep < 4; rep++) {
        const int local = rep * 64 + grp;
        const int d = cb * 256 + local;
        const bool vd = d < N;
        const int off = vd ? start_s[local] : 0;
        const int deg = vd ? hist[local] : 0;
        const float sdd = vd ? sdst[d] : 0.f;

        float M = -INFINITY, S = 0.f;
        float c0 = 0.f, c1 = 0.f, c2 = 0.f, c3 = 0.f;

        for (int ch = 0; ch < deg; ch += 16) {
            int ce = min(16, deg - ch);
            float score = -INFINITY;
            int s = 0;
            if (li < ce) {
                s = ssl[off + ch + li];
                float sc = sdd + ssrc[s];
                score = sc > 0.f ? sc : NEG_SLOPE * sc;
            }
            float mc = score;
            mc = fmaxf(mc, __shfl_xor(mc, 1));
            mc = fmaxf(mc, __shfl_xor(mc, 2));
            mc = fmaxf(mc, __shfl_xor(mc, 4));
            mc = fmaxf(mc, __shfl_xor(mc, 8));
            float newM = fmaxf(M, mc);
            float scale = __expf(M - newM);
            float w = (li < ce) ? __expf(score - newM) : 0.f;
            ws_sh[wid][lane] = make_float2(w, __int_as_float(s));
            float csum = w;
            csum += __shfl_xor(csum, 1);
            csum += __shfl_xor(csum, 2);
            csum += __shfl_xor(csum, 4);
            csum += __shfl_xor(csum, 8);
            S = S * scale + csum;
            __builtin_amdgcn_wave_barrier();

            float t0 = 0.f, t1 = 0.f, t2 = 0.f, t3 = 0.f;
#pragma unroll
            for (int e = 0; e < 16; e++) {
                float2 tw = ws_sh[wid][g * 16 + e];
                int se = __float_as_int(tw.y);
                ushort4 r = *(const ushort4*)(hb + (((size_t)(unsigned)se) << 6) + li * 4);
                t0 = fmaf(tw.x, bf2f(r.x), t0);
                t1 = fmaf(tw.x, bf2f(r.y), t1);
                t2 = fmaf(tw.x, bf2f(r.z), t2);
                t3 = fmaf(tw.x, bf2f(r.w), t3);
            }
            c0 = c0 * scale + t0;
            c1 = c1 * scale + t1;
            c2 = c2 * scale + t2;
            c3 = c3 * scale + t3;
            __builtin_amdgcn_wave_barrier();
            M = newM;
        }

        if (vd) {
            ushort4 hr = *(const ushort4*)(hb + (((size_t)(unsigned)d) << 6) + li * 4);
            float inv = (S > 0.f) ? 1.f / S : 0.f;
            float r0 = bf2f(hr.x) - c0 * inv;
            float r1 = bf2f(hr.y) - c1 * inv;
            float r2 = bf2f(hr.z) - c2 * inv;
            float r3 = bf2f(hr.w) - c3 * inv;
            float4 o;
            o.x = r0 > 0.f ? r0 : 0.f;
            o.y = r1 > 0.f ? r1 : 0.f;
            o.z = r2 > 0.f ? r2 : 0.f;
            o.w = r3 > 0.f ? r3 : 0.f;
            *(float4*)(out + (size_t)d * F_OUT + li * 4) = o;
        }
    }
}

// ---------------------------------------------------------------------------
extern "C" void kernel_launch(void* const* d_in, const int* in_sizes, int n_in,
                              void* d_out, int out_size, void* d_ws,
                              size_t ws_size, hipStream_t stream)
{
    const float* x  = (const float*)d_in[0];
    const float* W1 = (const float*)d_in[1];
    const float* W2 = (const float*)d_in[2];
    const float* a  = (const float*)d_in[3];
    const int* src  = (const int*)d_in[4];
    const int* dst  = (const int*)d_in[5];
    const int N = in_sizes[0] / F_IN;   // 50000
    const int E = in_sizes[4];          // 800000

    float* ws = (float*)d_ws;
    float* sdst = ws;                                   // N
    float* ssrc = sdst + N;                             // N
    unsigned short* w1fh = (unsigned short*)(ssrc + N); // 16384 us
    unsigned short* w1fl = w1fh + 16384;                // 16384 us
    unsigned short* w2fh = w1fl + 16384;                // 4096 us
    unsigned short* w2fl = w2fh + 4096;                 // 4096 us
    unsigned short* hb = w2fl + 4096;                   // N*64 us
    int* cursor = (int*)(hb + (size_t)N * F_OUT);       // 256
    int* edata  = cursor + 256;                         // 196*CAP

    const int nbc = (N + 255) >> 8;                     // 196
    const int MLPB = (N + 127) >> 7;                    // 391
    const int chunk = (E + SB - 1) / SB;                // 12500

    prep_kernel<<<64, 256, 0, stream>>>(W1, W2, w1fh, w1fl, w2fh, w2fl, cursor);
    mlp_scatter_kernel<<<MLPB + SB, 256, 0, stream>>>(x, w1fh, w1fl, w2fh, w2fl, a,
                                                      hb, sdst, ssrc, N,
                                                      src, dst, cursor, edata,
                                                      E, chunk, MLPB);
    sortagg_kernel<<<nbc, 1024, 0, stream>>>(cursor, edata, hb, sdst, ssrc,
                                             (float*)d_out, N);
}